// Round 2
// baseline (11332.139 us; speedup 1.0000x reference)
//
#include <hip/hip_runtime.h>
#include <hip/hip_bf16.h>
#include <stdint.h>

// Problem constants
constexpr int NB   = 128;   // batch
constexpr int NC   = 2;     // grid channels
constexpr int NH   = 150;   // hidden
constexpr int NA   = 8;     // actions
constexpr int KIT  = 30;    // VI iterations
constexpr int GN   = 49;    // grid spatial
constexpr int HPN  = 51;    // padded spatial (49+2)
constexpr int RTC  = 73;    // 1 reward + 72 trans channels

__device__ __forceinline__ float bf_lo(uint32_t u){ return __uint_as_float(u << 16); }
__device__ __forceinline__ float bf_hi(uint32_t u){ return __uint_as_float(u & 0xffff0000u); }

// Load element i of a buffer whose dtype is bf16 (isbf=1) or f32 (isbf=0), as float.
__device__ __forceinline__ float ld_f(const void* p, size_t i, int isbf) {
    if (isbf) {
        uint32_t b = ((const uint16_t*)p)[i];
        return __uint_as_float(b << 16);
    }
    return ((const float*)p)[i];
}
// Same, but return bf16 bits.
__device__ __forceinline__ uint16_t ld_bf_bits(const void* p, size_t i, int isbf) {
    if (isbf) return ((const uint16_t*)p)[i];
    float f = ((const float*)p)[i];
    uint32_t u = __float_as_uint(f);
    // round-to-nearest-even bf16 truncation
    uint32_t lsb = (u >> 16) & 1u;
    u += 0x7fffu + lsb;
    return (uint16_t)(u >> 16);
}

// ---------------- dtype sniffer: are float inputs bf16 or f32? --------------------------
// Read h2_w (scale ~0.05*N(0,1)) at even uint16 indices interpreted as bf16.
// If data is bf16: all values are sane magnitudes. If data is f32: these are mantissa
// halves -> random bits -> only ~5% decode to a sane bf16 magnitude.
__global__ void detect_kernel(const uint16_t* __restrict__ w, int* __restrict__ flag)
{
    int i = threadIdx.x;  // 0..63
    uint32_t bits = w[2 * i];
    float f = __uint_as_float(bits << 16);
    float a = fabsf(f);
    bool ok = (a >= 1e-10f && a <= 1e5f);
    unsigned long long m = __ballot(ok);
    if (i == 0) flag[0] = (__popcll(m) >= 48) ? 1 : 0;
}

// ---------------- prep: layout transforms (NCHW->channels-last, OIHW->[k][ci][co]) ---------
__global__ void prep_kernel(const void* __restrict__ g,
                            const void* __restrict__ w1,
                            const void* __restrict__ b1,
                            const void* __restrict__ w2,
                            const void* __restrict__ b2,
                            const void* __restrict__ rw,
                            const void* __restrict__ tw,
                            const void* __restrict__ a1w,
                            const void* __restrict__ a1b,
                            const void* __restrict__ a2w,
                            const void* __restrict__ a2b,
                            const int* __restrict__ flag,
                            uint16_t* __restrict__ grid_cl,
                            float* __restrict__ wT1, float* __restrict__ bias1,
                            float* __restrict__ wT2, float* __restrict__ bias2,
                            float* __restrict__ wTrt,
                            float* __restrict__ wA1, float* __restrict__ bA1,
                            float* __restrict__ wA2, float* __restrict__ bA2)
{
    constexpr int N_GRID = NB * GN * GN * NC;        // 614656
    constexpr int N_WT1  = 9 * NC * NH;              // 2700
    constexpr int N_B1   = NH;
    constexpr int N_WT2  = 9 * NH * NH;              // 202500
    constexpr int N_B2   = NH;
    constexpr int N_WTRT = 9 * NH * RTC;             // 98550
    constexpr int N_A1W  = NH * NA;                  // 1200
    constexpr int N_A1B  = NH;
    constexpr int N_A2W  = NA * NH;                  // 1200
    constexpr int N_A2B  = NA;

    int isbf = flag[0];
    int i = blockIdx.x * blockDim.x + threadIdx.x;
    if (i < N_GRID) {
        int c = i & 1; int s = (i >> 1) % (GN*GN); int b = i / (GN*GN*2);
        grid_cl[i] = ld_bf_bits(g, (size_t)(b*NC + c)*(GN*GN) + s, isbf);
        return;
    }
    i -= N_GRID;
    if (i < N_WT1) {
        int co = i % NH; int r = i / NH; int ci = r & 1; int k = r >> 1;
        wT1[i] = ld_f(w1, (size_t)co*(NC*9) + ci*9 + k, isbf);
        return;
    }
    i -= N_WT1;
    if (i < N_B1) { bias1[i] = ld_f(b1, i, isbf); return; }
    i -= N_B1;
    if (i < N_WT2) {
        int co = i % NH; int r = i / NH; int ci = r % NH; int k = r / NH;
        wT2[i] = ld_f(w2, (size_t)co*(NH*9) + ci*9 + k, isbf);
        return;
    }
    i -= N_WT2;
    if (i < N_B2) { bias2[i] = ld_f(b2, i, isbf); return; }
    i -= N_B2;
    if (i < N_WTRT) {
        int co = i % RTC; int r = i / RTC; int ci = r % NH; int k = r / NH;
        if (co == 0) wTrt[i] = ld_f(rw, ci*9 + k, isbf);
        else         wTrt[i] = ld_f(tw, (size_t)(co-1)*(NH*9) + ci*9 + k, isbf);
        return;
    }
    i -= N_WTRT;
    if (i < N_A1W) { wA1[i] = ld_f(a1w, i, isbf); return; }
    i -= N_A1W;
    if (i < N_A1B) { bA1[i] = ld_f(a1b, i, isbf); return; }
    i -= N_A1B;
    if (i < N_A2W) { wA2[i] = ld_f(a2w, i, isbf); return; }
    i -= N_A2W;
    if (i < N_A2B) { bA2[i] = ld_f(a2b, i, isbf); return; }
}

// ---------------- generic 3x3 conv, channels-last, lanes = co, 4 x-positions/block --------
template<int CI, int CO, int PAD, int OH, bool RELU, bool OBF>
__global__ void conv3x3_cl(const uint16_t* __restrict__ in,   // bf16 bits, [b][y][x][ci]
                           const float* __restrict__ wT,      // [(k*CI+ci)*CO + co]
                           const float* __restrict__ bias,    // f32 [CO] or null
                           void* __restrict__ outv)           // [b][y][x][co]
{
    constexpr int H  = GN;
    constexpr int XG = (OH + 3) / 4;
    int bid = blockIdx.x;
    int xg = bid % XG;
    int y  = (bid / XG) % OH;
    int b  = bid / (XG * OH);
    int x0 = xg * 4;
    int co = threadIdx.x;
    int cosafe = (co < CO) ? co : 0;

    float bv = 0.f;
    if (bias != nullptr && co < CO) bv = bias[co];
    float acc0 = bv, acc1 = bv, acc2 = bv, acc3 = bv;

    for (int ky = 0; ky < 3; ++ky) {
        int yy = y + ky - PAD;
        if (yy < 0 || yy >= H) continue;
        const uint16_t* rowp = in + (size_t)(b * H + yy) * H * CI;
        #pragma unroll
        for (int kx = 0; kx < 3; ++kx) {
            const float* wp = wT + (size_t)((ky*3 + kx) * CI) * CO + cosafe;
            int xb = x0 + kx - PAD;
            const uint16_t* p0; const uint16_t* p1; const uint16_t* p2; const uint16_t* p3;
            uint32_t m0, m1, m2, m3;
            {
                int xx0 = xb+0, xx1 = xb+1, xx2 = xb+2, xx3 = xb+3;
                int c0 = min(max(xx0,0),H-1), c1 = min(max(xx1,0),H-1);
                int c2 = min(max(xx2,0),H-1), c3 = min(max(xx3,0),H-1);
                p0 = rowp + (size_t)c0*CI; p1 = rowp + (size_t)c1*CI;
                p2 = rowp + (size_t)c2*CI; p3 = rowp + (size_t)c3*CI;
                m0 = (xx0 >= 0 && xx0 < H) ? 0xffffffffu : 0u;
                m1 = (xx1 >= 0 && xx1 < H) ? 0xffffffffu : 0u;
                m2 = (xx2 >= 0 && xx2 < H) ? 0xffffffffu : 0u;
                m3 = (xx3 >= 0 && xx3 < H) ? 0xffffffffu : 0u;
            }
            for (int ci = 0; ci < CI; ci += 2) {
                float w0 = wp[(size_t)ci * CO];
                float w1 = wp[(size_t)ci * CO + CO];
                uint32_t u0 = (*(const uint32_t*)(p0 + ci)) & m0;
                uint32_t u1 = (*(const uint32_t*)(p1 + ci)) & m1;
                uint32_t u2 = (*(const uint32_t*)(p2 + ci)) & m2;
                uint32_t u3 = (*(const uint32_t*)(p3 + ci)) & m3;
                acc0 += bf_lo(u0)*w0 + bf_hi(u0)*w1;
                acc1 += bf_lo(u1)*w0 + bf_hi(u1)*w1;
                acc2 += bf_lo(u2)*w0 + bf_hi(u2)*w1;
                acc3 += bf_lo(u3)*w0 + bf_hi(u3)*w1;
            }
        }
    }

    if (co < CO) {
        float accs[4] = {acc0, acc1, acc2, acc3};
        #pragma unroll
        for (int xi = 0; xi < 4; ++xi) {
            int x = x0 + xi;
            if (x >= OH) break;
            float r = accs[xi];
            if (RELU) r = fmaxf(r, 0.f);
            size_t oi = ((size_t)(b*OH + y)*OH + x) * CO + co;
            if (OBF) {
                uint32_t u = __float_as_uint(r);
                uint32_t lsb = (u >> 16) & 1u;
                u += 0x7fffu + lsb;
                ((uint16_t*)outv)[oi] = (uint16_t)(u >> 16);
            } else {
                ((float*)outv)[oi] = r;
            }
        }
    }
}

// ---------------- softmax over the 9 transition taps, in place in rt --------------------
__global__ void softmax_kernel(float* __restrict__ rt)
{
    int idx = blockIdx.x * blockDim.x + threadIdx.x;
    constexpr int TOT = NB * HPN * HPN * NA;
    if (idx >= TOT) return;
    int a = idx & 7;
    size_t p = (size_t)(idx >> 3);
    float* t = rt + p * RTC + 1 + a * 9;
    float v[9];
    float m = -1e30f;
    #pragma unroll
    for (int k = 0; k < 9; ++k) { v[k] = t[k]; m = fmaxf(m, v[k]); }
    float s = 0.f;
    #pragma unroll
    for (int k = 0; k < 9; ++k) { v[k] = expf(v[k] - m); s += v[k]; }
    float inv = 1.f / s;
    #pragma unroll
    for (int k = 0; k < 9; ++k) t[k] = v[k] * inv;
}

// ---------------- persistent value iteration: one block per batch, v in LDS --------------
__global__ void vi_kernel(const float* __restrict__ rt, float* __restrict__ qout)
{
    __shared__ float vb[2][53*53];
    __shared__ float rew[HPN*HPN];
    int b = blockIdx.x, t = threadIdx.x;
    int bs = blockDim.x;
    for (int i = t; i < 53*53; i += bs) { vb[0][i] = 0.f; vb[1][i] = 0.f; }
    const float* rtb = rt + (size_t)b * (HPN*HPN) * RTC;
    for (int i = t; i < HPN*HPN; i += bs) rew[i] = rtb[(size_t)i * RTC];
    __syncthreads();
    int cur = 0;
    for (int it = 0; it < KIT; ++it) {
        for (int p = t; p < HPN*HPN; p += bs) {
            int y = p / HPN, x = p % HPN;
            float pat[9];
            #pragma unroll
            for (int dy = 0; dy < 3; ++dy)
                #pragma unroll
                for (int dx = 0; dx < 3; ++dx)
                    pat[dy*3+dx] = vb[cur][(y+dy)*53 + (x+dx)];
            const float* s = rtb + (size_t)p * RTC + 1;
            float r = rew[p];
            float best = -1e30f;
            float qv[NA];
            #pragma unroll
            for (int a = 0; a < NA; ++a) {
                float qa = r;
                #pragma unroll
                for (int k = 0; k < 9; ++k) qa += s[a*9+k] * pat[k];
                qv[a] = qa;
                best = fmaxf(best, qa);
            }
            vb[cur^1][(y+1)*53 + (x+1)] = best;
            if (it == KIT-1) {
                #pragma unroll
                for (int a = 0; a < NA; ++a)
                    qout[((size_t)b*(HPN*HPN) + p)*NA + a] = qv[a];
            }
        }
        __syncthreads();
        cur ^= 1;
    }
}

// ---------------- fused MLP head: q(8) -> relu(150) -> logits(8) -------------------------
__global__ void head_kernel(const float* __restrict__ q,
                            const float* __restrict__ wA1,
                            const float* __restrict__ bA1,
                            const float* __restrict__ wA2,
                            const float* __restrict__ bA2,
                            const int* __restrict__ flag,
                            void* __restrict__ out)
{
    __shared__ float w1[NH*NA], sb1[NH], w2[NA*NH], sb2[NA];
    int t = threadIdx.x;
    for (int i = t; i < NH*NA; i += 256) w1[i] = wA1[i];
    for (int i = t; i < NH;    i += 256) sb1[i] = bA1[i];
    for (int i = t; i < NA*NH; i += 256) w2[i] = wA2[i];
    if (t < NA) sb2[t] = bA2[t];
    __syncthreads();

    int isbf = flag[0];
    int idx = blockIdx.x * 256 + t;
    constexpr int TOT = NB * GN * GN;
    if (idx >= TOT) return;
    int x = idx % GN, y = (idx / GN) % GN, b = idx / (GN*GN);
    const float* qp = q + ((size_t)(b*HPN + y)*HPN + x) * NA;
    float qv[NA];
    #pragma unroll
    for (int a = 0; a < NA; ++a) qv[a] = qp[a];
    float lg[NA];
    #pragma unroll
    for (int a = 0; a < NA; ++a) lg[a] = sb2[a];
    for (int c = 0; c < NH; ++c) {
        float m = sb1[c];
        #pragma unroll
        for (int a = 0; a < NA; ++a) m += qv[a] * w1[c*NA + a];
        m = fmaxf(m, 0.f);
        #pragma unroll
        for (int a = 0; a < NA; ++a) lg[a] += m * w2[a*NH + c];
    }
    #pragma unroll
    for (int a = 0; a < NA; ++a) {
        size_t oi = ((size_t)(b*NA + a)*GN + y)*GN + x;
        float r = lg[a];
        if (isbf) {
            uint32_t u = __float_as_uint(r);
            uint32_t lsb = (u >> 16) & 1u;
            u += 0x7fffu + lsb;
            ((uint16_t*)out)[oi] = (uint16_t)(u >> 16);
        } else {
            ((float*)out)[oi] = r;
        }
    }
}

extern "C" void kernel_launch(void* const* d_in, const int* in_sizes, int n_in,
                              void* d_out, int out_size, void* d_ws, size_t ws_size,
                              hipStream_t stream)
{
    const void* g   = d_in[0];
    // d_in[1], d_in[2] = x_coord, y_coord (unused by reference)
    const void* h1w = d_in[3];
    const void* h1b = d_in[4];
    const void* h2w = d_in[5];
    const void* h2b = d_in[6];
    const void* rw  = d_in[7];
    const void* tw  = d_in[8];
    const void* a1w = d_in[9];
    const void* a1b = d_in[10];
    const void* a2w = d_in[11];
    const void* a2b = d_in[12];

    char* ws = (char*)d_ws;
    size_t off = 0;
    auto take = [&](size_t bytes) { size_t r = off; off = (off + bytes + 255) & ~(size_t)255; return r; };

    constexpr size_t N_GRID_CL = (size_t)NB*GN*GN*NC;           // bf16
    constexpr size_t N_WT1  = 9*NC*NH;                          // f32
    constexpr size_t N_B1   = NH;
    constexpr size_t N_WT2  = 9*NH*NH;
    constexpr size_t N_B2   = NH;
    constexpr size_t N_WTRT = 9*NH*RTC;
    constexpr size_t N_A1W  = NH*NA;
    constexpr size_t N_A1B  = NH;
    constexpr size_t N_A2W  = NA*NH;
    constexpr size_t N_A2B  = NA;
    constexpr size_t N_H    = (size_t)NB*GN*GN*NH;              // bf16 (h1 / h2)
    constexpr size_t N_RT   = (size_t)NB*HPN*HPN*RTC;           // f32
    constexpr size_t N_Q    = (size_t)NB*HPN*HPN*NA;            // f32

    size_t off_flag   = take(4);
    size_t off_gridcl = take(N_GRID_CL * 2);
    size_t off_wT1    = take(N_WT1 * 4);
    size_t off_b1     = take(N_B1 * 4);
    size_t off_wT2    = take(N_WT2 * 4);
    size_t off_b2     = take(N_B2 * 4);
    size_t off_wTrt   = take(N_WTRT * 4);
    size_t off_wA1    = take(N_A1W * 4);
    size_t off_bA1    = take(N_A1B * 4);
    size_t off_wA2    = take(N_A2W * 4);
    size_t off_bA2    = take(N_A2B * 4);
    size_t off_q      = take(N_Q * 4);
    // region A: h1 (bf16) first, later reused for rt (f32) after conv2 consumed h1
    size_t szA = N_RT * 4 > N_H * 2 ? N_RT * 4 : N_H * 2;
    size_t off_A      = take(szA);
    size_t off_h2     = take(N_H * 2);

    int*   flag  = (int*)(ws + off_flag);
    uint16_t* grid_cl = (uint16_t*)(ws + off_gridcl);
    float* wT1   = (float*)(ws + off_wT1);
    float* bias1 = (float*)(ws + off_b1);
    float* wT2   = (float*)(ws + off_wT2);
    float* bias2 = (float*)(ws + off_b2);
    float* wTrt  = (float*)(ws + off_wTrt);
    float* wA1   = (float*)(ws + off_wA1);
    float* bA1   = (float*)(ws + off_bA1);
    float* wA2   = (float*)(ws + off_wA2);
    float* bA2   = (float*)(ws + off_bA2);
    float* qbuf  = (float*)(ws + off_q);
    uint16_t* h1 = (uint16_t*)(ws + off_A);
    float*    rt = (float*)(ws + off_A);
    uint16_t* h2 = (uint16_t*)(ws + off_h2);

    // 0. dtype detection (bf16 vs f32 inputs)
    detect_kernel<<<1, 64, 0, stream>>>((const uint16_t*)h2w, flag);
    // 1. layout prep + dtype conversion
    {
        int total = (int)(N_GRID_CL + N_WT1 + N_B1 + N_WT2 + N_B2 + N_WTRT
                          + N_A1W + N_A1B + N_A2W + N_A2B);
        prep_kernel<<<(total + 255)/256, 256, 0, stream>>>(
            g, h1w, h1b, h2w, h2b, rw, tw, a1w, a1b, a2w, a2b, flag,
            grid_cl, wT1, bias1, wT2, bias2, wTrt, wA1, bA1, wA2, bA2);
    }
    // 2. conv1: 2->150, pad 1, relu, out 49x49 (bf16)
    conv3x3_cl<NC, NH, 1, GN, true, true>
        <<<NB*GN*((GN+3)/4), 192, 0, stream>>>(grid_cl, wT1, bias1, (void*)h1);
    // 3. conv2: 150->150, pad 1, relu (bf16)
    conv3x3_cl<NH, NH, 1, GN, true, true>
        <<<NB*GN*((GN+3)/4), 192, 0, stream>>>(h1, wT2, bias2, (void*)h2);
    // 4. reward+trans: 150->73, pad 2, out 51x51 (f32, overwrites h1 region)
    conv3x3_cl<NH, RTC, 2, HPN, false, false>
        <<<NB*HPN*((HPN+3)/4), 128, 0, stream>>>(h2, wTrt, nullptr, (void*)rt);
    // 5. softmax over 9 taps, in place
    softmax_kernel<<<(NB*HPN*HPN*NA + 255)/256, 256, 0, stream>>>(rt);
    // 6. value iteration (persistent, one block per batch)
    vi_kernel<<<NB, 512, 0, stream>>>(rt, qbuf);
    // 7. head
    head_kernel<<<(NB*GN*GN + 255)/256, 256, 0, stream>>>(qbuf, wA1, bA1, wA2, bA2, flag,
                                                          d_out);
}

// Round 3
// 2299.991 us; speedup vs baseline: 4.9270x; 4.9270x over previous
//
#include <hip/hip_runtime.h>
#include <hip/hip_bf16.h>
#include <stdint.h>

// Problem constants
constexpr int NB   = 128;   // batch
constexpr int NC   = 2;     // grid channels
constexpr int NH   = 150;   // hidden
constexpr int NA   = 8;     // actions
constexpr int KIT  = 30;    // VI iterations
constexpr int GN   = 49;    // grid spatial
constexpr int HPN  = 51;    // padded spatial (49+2)
constexpr int RTC  = 73;    // 1 reward + 72 trans channels
constexpr int CIP  = 160;   // padded channel count (multiple of 32)

typedef short v8bf __attribute__((ext_vector_type(8)));
typedef float v4f  __attribute__((ext_vector_type(4)));

__device__ __forceinline__ float bf_lo(uint32_t u){ return __uint_as_float(u << 16); }
__device__ __forceinline__ float bf_hi(uint32_t u){ return __uint_as_float(u & 0xffff0000u); }

__device__ __forceinline__ uint16_t f2bf(float f) {
    uint32_t u = __float_as_uint(f);
    uint32_t lsb = (u >> 16) & 1u;
    u += 0x7fffu + lsb;
    return (uint16_t)(u >> 16);
}

// Load element i of a buffer whose dtype is bf16 (isbf=1) or f32 (isbf=0), as float.
__device__ __forceinline__ float ld_f(const void* p, size_t i, int isbf) {
    if (isbf) {
        uint32_t b = ((const uint16_t*)p)[i];
        return __uint_as_float(b << 16);
    }
    return ((const float*)p)[i];
}
__device__ __forceinline__ uint16_t ld_bf_bits(const void* p, size_t i, int isbf) {
    if (isbf) return ((const uint16_t*)p)[i];
    return f2bf(((const float*)p)[i]);
}

// ---------------- dtype sniffer ---------------------------------------------------------
__global__ void detect_kernel(const uint16_t* __restrict__ w, int* __restrict__ flag)
{
    int i = threadIdx.x;  // 0..63
    uint32_t bits = w[2 * i];
    float f = __uint_as_float(bits << 16);
    float a = fabsf(f);
    bool ok = (a >= 1e-10f && a <= 1e5f);
    unsigned long long m = __ballot(ok);
    if (i == 0) flag[0] = (__popcll(m) >= 48) ? 1 : 0;
}

// ---------------- prep: layout transforms -----------------------------------------------
// grid_cl [b][49][49][2] bf16 ; wT1 f32 [(k*2+ci)*150+co] ; bias1 f32[150]
// w2t bf16 [9][160][160] (tap, co, ci; zero padded) ; bias2 f32[160]
// wrt bf16 [9][80][160]  (co0 = reward, co1..72 = trans, zero padded)
// wA1/bA1/wA2/bA2 f32
__global__ void prep_kernel(const void* __restrict__ g,
                            const void* __restrict__ w1,
                            const void* __restrict__ b1,
                            const void* __restrict__ w2,
                            const void* __restrict__ b2,
                            const void* __restrict__ rw,
                            const void* __restrict__ tw,
                            const void* __restrict__ a1w,
                            const void* __restrict__ a1b,
                            const void* __restrict__ a2w,
                            const void* __restrict__ a2b,
                            const int* __restrict__ flag,
                            uint16_t* __restrict__ grid_cl,
                            float* __restrict__ wT1, float* __restrict__ bias1,
                            uint16_t* __restrict__ w2t, float* __restrict__ bias2,
                            uint16_t* __restrict__ wrt,
                            float* __restrict__ wA1, float* __restrict__ bA1,
                            float* __restrict__ wA2, float* __restrict__ bA2)
{
    constexpr int N_GRID = NB * GN * GN * NC;        // 614656
    constexpr int N_WT1  = 9 * NC * NH;              // 2700
    constexpr int N_B1   = NH;
    constexpr int N_W2T  = 9 * CIP * CIP;            // 230400
    constexpr int N_B2   = CIP;
    constexpr int N_WRT  = 9 * 80 * CIP;             // 115200
    constexpr int N_A1W  = NH * NA;
    constexpr int N_A1B  = NH;
    constexpr int N_A2W  = NA * NH;
    constexpr int N_A2B  = NA;

    int isbf = flag[0];
    int i = blockIdx.x * blockDim.x + threadIdx.x;
    if (i < N_GRID) {
        int c = i & 1; int s = (i >> 1) % (GN*GN); int b = i / (GN*GN*2);
        grid_cl[i] = ld_bf_bits(g, (size_t)(b*NC + c)*(GN*GN) + s, isbf);
        return;
    }
    i -= N_GRID;
    if (i < N_WT1) {
        int co = i % NH; int r = i / NH; int ci = r & 1; int k = r >> 1;
        wT1[i] = ld_f(w1, (size_t)co*(NC*9) + ci*9 + k, isbf);
        return;
    }
    i -= N_WT1;
    if (i < N_B1) { bias1[i] = ld_f(b1, i, isbf); return; }
    i -= N_B1;
    if (i < N_W2T) {
        int ci = i % CIP; int r = i / CIP; int co = r % CIP; int tap = r / CIP;
        uint16_t v = 0;
        if (co < NH && ci < NH)
            v = f2bf(ld_f(w2, ((size_t)co*NH + ci)*9 + tap, isbf));
        w2t[i] = v;
        return;
    }
    i -= N_W2T;
    if (i < N_B2) { bias2[i] = (i < NH) ? ld_f(b2, i, isbf) : 0.f; return; }
    i -= N_B2;
    if (i < N_WRT) {
        int ci = i % CIP; int r = i / CIP; int co = r % 80; int tap = r / 80;
        uint16_t v = 0;
        if (ci < NH) {
            if (co == 0)           v = f2bf(ld_f(rw, (size_t)ci*9 + tap, isbf));
            else if (co <= 72)     v = f2bf(ld_f(tw, ((size_t)(co-1)*NH + ci)*9 + tap, isbf));
        }
        wrt[i] = v;
        return;
    }
    i -= N_WRT;
    if (i < N_A1W) { wA1[i] = ld_f(a1w, i, isbf); return; }
    i -= N_A1W;
    if (i < N_A1B) { bA1[i] = ld_f(a1b, i, isbf); return; }
    i -= N_A1B;
    if (i < N_A2W) { wA2[i] = ld_f(a2w, i, isbf); return; }
    i -= N_A2W;
    if (i < N_A2B) { bA2[i] = ld_f(a2b, i, isbf); return; }
}

// ---------------- conv1: 2->150 VALU, writes 160-padded bf16 ----------------------------
__global__ __launch_bounds__(192)
void conv1_cl(const uint16_t* __restrict__ in,   // [b][49][49][2] bf16
              const float* __restrict__ wT,      // [(k*2+ci)*150+co]
              const float* __restrict__ bias,    // f32 [150]
              uint16_t* __restrict__ out)        // [b][49][49][160] bf16
{
    constexpr int H = GN, XG = 13;
    int bid = blockIdx.x;
    int xg = bid % XG;
    int y  = (bid / XG) % H;
    int b  = bid / (XG * H);
    int x0 = xg * 4;
    int co = threadIdx.x;

    if (co >= NH) {
        // zero-fill pad channels 150..159
        if (co < CIP) {
            #pragma unroll
            for (int xi = 0; xi < 4; ++xi) {
                int x = x0 + xi;
                if (x < H) out[((size_t)(b*H + y)*H + x)*CIP + co] = 0;
            }
        }
        return;
    }

    float bv = bias[co];
    float acc[4] = {bv, bv, bv, bv};

    for (int ky = 0; ky < 3; ++ky) {
        int yy = y + ky - 1;
        if (yy < 0 || yy >= H) continue;
        const uint16_t* rowp = in + (size_t)(b * H + yy) * H * NC;
        #pragma unroll
        for (int kx = 0; kx < 3; ++kx) {
            const float* wp = wT + ((ky*3 + kx) * NC) * NH + co;
            float w0 = wp[0];
            float w1 = wp[NH];
            #pragma unroll
            for (int xi = 0; xi < 4; ++xi) {
                int xx = x0 + xi + kx - 1;
                if (xx < 0 || xx >= H) continue;
                uint32_t u = *(const uint32_t*)(rowp + (size_t)xx * NC);
                acc[xi] += bf_lo(u)*w0 + bf_hi(u)*w1;
            }
        }
    }
    #pragma unroll
    for (int xi = 0; xi < 4; ++xi) {
        int x = x0 + xi;
        if (x < H) out[((size_t)(b*H + y)*H + x)*CIP + co] = f2bf(fmaxf(acc[xi], 0.f));
    }
}

// ---------------- MFMA implicit-GEMM 3x3 conv -------------------------------------------
// Input: [b][49][49][160] bf16 (padded). Weights: [9][CO_T][160] bf16 (padded).
// Block: 192 threads (3 waves). Tile: M=96 (6 rows x 16 cols), N=CO_T.
// Wave w handles output rows y0+2w, y0+2w+1.
template<int CO_T, int PAD, int OH, bool RELU, bool OBF>
__global__ __launch_bounds__(192)
void conv_mfma(const uint16_t* __restrict__ in,
               const uint16_t* __restrict__ wt,
               const float* __restrict__ bias,
               void* __restrict__ outv)
{
    constexpr int H = GN;
    constexpr int NSUB = CO_T / 16;
    constexpr int RG = 9, XG = 4;
    constexpr int ASTR = 168;          // LDS ci stride (shorts): 20i-word pattern, 2-way max
    static_assert(NSUB * 16 == CO_T, "");

    __shared__ __align__(16) uint16_t shA[8 * 18 * ASTR];   // halo: 8 rows x 18 cols
    __shared__ __align__(16) uint16_t shB[CO_T * 40];       // [co][32 ci + 8 pad]

    int bid = blockIdx.x;
    int xg = bid & 3;
    int rg = (bid >> 2) % RG;
    int b  = bid / (RG * XG);
    int y0 = rg * 6, x0 = xg * 16;
    int t = threadIdx.x;
    int w = t >> 6, l = t & 63;

    // ---- stage halo: 8*18*20 = 2880 chunks of 16B
    for (int q = t; q < 8*18*20; q += 192) {
        int ci8 = q % 20;
        int c   = (q / 20) % 18;
        int r   = q / 360;
        int yy = y0 + r - PAD;
        int xx = x0 + c - PAD;
        uint4 val = make_uint4(0u, 0u, 0u, 0u);
        if (yy >= 0 && yy < H && xx >= 0 && xx < H)
            val = *(const uint4*)(in + ((size_t)(b*H + yy)*H + xx)*CIP + ci8*8);
        *(uint4*)(shA + (r*18 + c)*ASTR + ci8*8) = val;
    }

    v4f acc[2][NSUB];
    #pragma unroll
    for (int s = 0; s < 2; ++s)
        #pragma unroll
        for (int n = 0; n < NSUB; ++n)
            acc[s][n] = (v4f){0.f, 0.f, 0.f, 0.f};

    int lo16 = l & 15, q4 = l >> 4;

    for (int tap = 0; tap < 9; ++tap) {
        int ky = tap / 3, kx = tap % 3;
        for (int kc = 0; kc < 5; ++kc) {
            if (tap | kc) __syncthreads();      // protect shB reuse
            // ---- stage B chunk: CO_T rows x 32 ci (4 x 16B per row)
            for (int q = t; q < CO_T*4; q += 192) {
                int c4 = q & 3, co = q >> 2;
                uint4 v = *(const uint4*)(wt + ((size_t)tap*CO_T + co)*CIP + kc*32 + c4*8);
                *(uint4*)(shB + co*40 + c4*8) = v;
            }
            __syncthreads();

            int ci = kc*32 + q4*8;
            v8bf afr[2];
            #pragma unroll
            for (int s = 0; s < 2; ++s) {
                int r = 2*w + s + ky;
                int c = lo16 + kx;
                afr[s] = *(const v8bf*)(shA + (r*18 + c)*ASTR + ci);
            }
            #pragma unroll
            for (int n = 0; n < NSUB; ++n) {
                v8bf bfr = *(const v8bf*)(shB + (n*16 + lo16)*40 + q4*8);
                acc[0][n] = __builtin_amdgcn_mfma_f32_16x16x32_bf16(afr[0], bfr, acc[0][n], 0, 0, 0);
                acc[1][n] = __builtin_amdgcn_mfma_f32_16x16x32_bf16(afr[1], bfr, acc[1][n], 0, 0, 0);
            }
        }
    }

    // ---- epilogue: C/D layout: co = n*16 + (l&15), x = x0 + q4*4 + reg
    #pragma unroll
    for (int s = 0; s < 2; ++s) {
        int y = y0 + 2*w + s;
        if (y >= OH) continue;
        #pragma unroll
        for (int n = 0; n < NSUB; ++n) {
            int co = n*16 + lo16;
            float bv = bias ? bias[co] : 0.f;
            #pragma unroll
            for (int r = 0; r < 4; ++r) {
                int x = x0 + q4*4 + r;
                if (x >= OH) continue;
                float v = acc[s][n][r] + bv;
                if (RELU) v = fmaxf(v, 0.f);
                if (OBF) {
                    ((uint16_t*)outv)[((size_t)(b*OH + y)*OH + x)*CIP + co] = f2bf(v);
                } else {
                    if (co < RTC)
                        ((float*)outv)[((size_t)(b*OH + y)*OH + x)*RTC + co] = v;
                }
            }
        }
    }
}

// ---------------- softmax over the 9 transition taps, in place in rt --------------------
__global__ void softmax_kernel(float* __restrict__ rt)
{
    int idx = blockIdx.x * blockDim.x + threadIdx.x;
    constexpr int TOT = NB * HPN * HPN * NA;
    if (idx >= TOT) return;
    int a = idx & 7;
    size_t p = (size_t)(idx >> 3);
    float* tp = rt + p * RTC + 1 + a * 9;
    float v[9];
    float m = -1e30f;
    #pragma unroll
    for (int k = 0; k < 9; ++k) { v[k] = tp[k]; m = fmaxf(m, v[k]); }
    float s = 0.f;
    #pragma unroll
    for (int k = 0; k < 9; ++k) { v[k] = expf(v[k] - m); s += v[k]; }
    float inv = 1.f / s;
    #pragma unroll
    for (int k = 0; k < 9; ++k) tp[k] = v[k] * inv;
}

// ---------------- persistent value iteration: one block per batch, v in LDS --------------
__global__ void vi_kernel(const float* __restrict__ rt, float* __restrict__ qout)
{
    __shared__ float vb[2][53*53];
    __shared__ float rew[HPN*HPN];
    int b = blockIdx.x, t = threadIdx.x;
    int bs = blockDim.x;
    for (int i = t; i < 53*53; i += bs) { vb[0][i] = 0.f; vb[1][i] = 0.f; }
    const float* rtb = rt + (size_t)b * (HPN*HPN) * RTC;
    for (int i = t; i < HPN*HPN; i += bs) rew[i] = rtb[(size_t)i * RTC];
    __syncthreads();
    int cur = 0;
    for (int it = 0; it < KIT; ++it) {
        for (int p = t; p < HPN*HPN; p += bs) {
            int y = p / HPN, x = p % HPN;
            float pat[9];
            #pragma unroll
            for (int dy = 0; dy < 3; ++dy)
                #pragma unroll
                for (int dx = 0; dx < 3; ++dx)
                    pat[dy*3+dx] = vb[cur][(y+dy)*53 + (x+dx)];
            const float* s = rtb + (size_t)p * RTC + 1;
            float r = rew[p];
            float best = -1e30f;
            float qv[NA];
            #pragma unroll
            for (int a = 0; a < NA; ++a) {
                float qa = r;
                #pragma unroll
                for (int k = 0; k < 9; ++k) qa += s[a*9+k] * pat[k];
                qv[a] = qa;
                best = fmaxf(best, qa);
            }
            vb[cur^1][(y+1)*53 + (x+1)] = best;
            if (it == KIT-1) {
                #pragma unroll
                for (int a = 0; a < NA; ++a)
                    qout[((size_t)b*(HPN*HPN) + p)*NA + a] = qv[a];
            }
        }
        __syncthreads();
        cur ^= 1;
    }
}

// ---------------- fused MLP head: q(8) -> relu(150) -> logits(8) -------------------------
__global__ void head_kernel(const float* __restrict__ q,
                            const float* __restrict__ wA1,
                            const float* __restrict__ bA1,
                            const float* __restrict__ wA2,
                            const float* __restrict__ bA2,
                            const int* __restrict__ flag,
                            void* __restrict__ out)
{
    __shared__ float w1[NH*NA], sb1[NH], w2[NA*NH], sb2[NA];
    int t = threadIdx.x;
    for (int i = t; i < NH*NA; i += 256) w1[i] = wA1[i];
    for (int i = t; i < NH;    i += 256) sb1[i] = bA1[i];
    for (int i = t; i < NA*NH; i += 256) w2[i] = wA2[i];
    if (t < NA) sb2[t] = bA2[t];
    __syncthreads();

    int isbf = flag[0];
    int idx = blockIdx.x * 256 + t;
    constexpr int TOT = NB * GN * GN;
    if (idx >= TOT) return;
    int x = idx % GN, y = (idx / GN) % GN, b = idx / (GN*GN);
    const float* qp = q + ((size_t)(b*HPN + y)*HPN + x) * NA;
    float qv[NA];
    #pragma unroll
    for (int a = 0; a < NA; ++a) qv[a] = qp[a];
    float lg[NA];
    #pragma unroll
    for (int a = 0; a < NA; ++a) lg[a] = sb2[a];
    for (int c = 0; c < NH; ++c) {
        float m = sb1[c];
        #pragma unroll
        for (int a = 0; a < NA; ++a) m += qv[a] * w1[c*NA + a];
        m = fmaxf(m, 0.f);
        #pragma unroll
        for (int a = 0; a < NA; ++a) lg[a] += m * w2[a*NH + c];
    }
    #pragma unroll
    for (int a = 0; a < NA; ++a) {
        size_t oi = ((size_t)(b*NA + a)*GN + y)*GN + x;
        float r = lg[a];
        if (isbf) ((uint16_t*)out)[oi] = f2bf(r);
        else      ((float*)out)[oi] = r;
    }
}

extern "C" void kernel_launch(void* const* d_in, const int* in_sizes, int n_in,
                              void* d_out, int out_size, void* d_ws, size_t ws_size,
                              hipStream_t stream)
{
    const void* g   = d_in[0];
    const void* h1w = d_in[3];
    const void* h1b = d_in[4];
    const void* h2w = d_in[5];
    const void* h2b = d_in[6];
    const void* rw  = d_in[7];
    const void* tw  = d_in[8];
    const void* a1w = d_in[9];
    const void* a1b = d_in[10];
    const void* a2w = d_in[11];
    const void* a2b = d_in[12];

    char* ws = (char*)d_ws;
    size_t off = 0;
    auto take = [&](size_t bytes) { size_t r = off; off = (off + bytes + 255) & ~(size_t)255; return r; };

    constexpr size_t N_GRID_CL = (size_t)NB*GN*GN*NC;           // bf16
    constexpr size_t N_WT1  = 9*NC*NH;                          // f32
    constexpr size_t N_B1   = NH;
    constexpr size_t N_W2T  = 9*CIP*CIP;                        // bf16
    constexpr size_t N_B2   = CIP;
    constexpr size_t N_WRT  = 9*80*CIP;                         // bf16
    constexpr size_t N_A1W  = NH*NA;
    constexpr size_t N_A1B  = NH;
    constexpr size_t N_A2W  = NA*NH;
    constexpr size_t N_A2B  = NA;
    constexpr size_t N_H    = (size_t)NB*GN*GN*CIP;             // bf16 (h1 / h2, padded)
    constexpr size_t N_RT   = (size_t)NB*HPN*HPN*RTC;           // f32
    constexpr size_t N_Q    = (size_t)NB*HPN*HPN*NA;            // f32

    size_t off_flag   = take(4);
    size_t off_gridcl = take(N_GRID_CL * 2);
    size_t off_wT1    = take(N_WT1 * 4);
    size_t off_b1     = take(N_B1 * 4);
    size_t off_w2t    = take(N_W2T * 2);
    size_t off_b2     = take(N_B2 * 4);
    size_t off_wrt    = take(N_WRT * 2);
    size_t off_wA1    = take(N_A1W * 4);
    size_t off_bA1    = take(N_A1B * 4);
    size_t off_wA2    = take(N_A2W * 4);
    size_t off_bA2    = take(N_A2B * 4);
    size_t off_q      = take(N_Q * 4);
    // region A: h1 (bf16, padded) first; later reused for rt (f32) after conv2 consumed h1
    size_t szA = (N_RT * 4 > N_H * 2) ? N_RT * 4 : N_H * 2;
    size_t off_A      = take(szA);
    size_t off_h2     = take(N_H * 2);

    int*      flag    = (int*)(ws + off_flag);
    uint16_t* grid_cl = (uint16_t*)(ws + off_gridcl);
    float*    wT1     = (float*)(ws + off_wT1);
    float*    bias1   = (float*)(ws + off_b1);
    uint16_t* w2t     = (uint16_t*)(ws + off_w2t);
    float*    bias2   = (float*)(ws + off_b2);
    uint16_t* wrt     = (uint16_t*)(ws + off_wrt);
    float*    wA1     = (float*)(ws + off_wA1);
    float*    bA1     = (float*)(ws + off_bA1);
    float*    wA2     = (float*)(ws + off_wA2);
    float*    bA2     = (float*)(ws + off_bA2);
    float*    qbuf    = (float*)(ws + off_q);
    uint16_t* h1      = (uint16_t*)(ws + off_A);
    float*    rt      = (float*)(ws + off_A);
    uint16_t* h2      = (uint16_t*)(ws + off_h2);

    // 0. dtype detection (bf16 vs f32 inputs)
    detect_kernel<<<1, 64, 0, stream>>>((const uint16_t*)h2w, flag);
    // 1. layout prep + dtype conversion
    {
        int total = (int)(N_GRID_CL + N_WT1 + N_B1 + N_W2T + N_B2 + N_WRT
                          + N_A1W + N_A1B + N_A2W + N_A2B);
        prep_kernel<<<(total + 255)/256, 256, 0, stream>>>(
            g, h1w, h1b, h2w, h2b, rw, tw, a1w, a1b, a2w, a2b, flag,
            grid_cl, wT1, bias1, w2t, bias2, wrt, wA1, bA1, wA2, bA2);
    }
    // 2. conv1: 2->150 VALU, out [b][49][49][160] bf16
    conv1_cl<<<NB*GN*13, 192, 0, stream>>>(grid_cl, wT1, bias1, h1);
    // 3. conv2: 150->150 MFMA implicit GEMM, out h2 padded bf16
    conv_mfma<CIP, 1, GN, true, true>
        <<<NB*9*4, 192, 0, stream>>>(h1, w2t, bias2, (void*)h2);
    // 4. reward+trans: 150->73 MFMA, pad 2, out 51x51 f32 (overwrites h1 region)
    conv_mfma<80, 2, HPN, false, false>
        <<<NB*9*4, 192, 0, stream>>>(h2, wrt, nullptr, (void*)rt);
    // 5. softmax over 9 taps, in place
    softmax_kernel<<<(NB*HPN*HPN*NA + 255)/256, 256, 0, stream>>>(rt);
    // 6. value iteration (persistent, one block per batch)
    vi_kernel<<<NB, 512, 0, stream>>>(rt, qbuf);
    // 7. head
    head_kernel<<<(NB*GN*GN + 255)/256, 256, 0, stream>>>(qbuf, wA1, bA1, wA2, bA2, flag,
                                                          d_out);
}

// Round 4
// 1594.035 us; speedup vs baseline: 7.1091x; 1.4429x over previous
//
#include <hip/hip_runtime.h>
#include <hip/hip_bf16.h>
#include <stdint.h>

// Problem constants
constexpr int NB   = 128;   // batch
constexpr int NC   = 2;     // grid channels
constexpr int NH   = 150;   // hidden
constexpr int NA   = 8;     // actions
constexpr int KIT  = 30;    // VI iterations
constexpr int GN   = 49;    // grid spatial
constexpr int HPN  = 51;    // padded spatial (49+2)
constexpr int NP   = HPN * HPN;  // 2601 positions
constexpr int RTC  = 73;    // 1 reward + 72 trans channels
constexpr int CIP  = 160;   // padded channel count (multiple of 32)

typedef short v8bf __attribute__((ext_vector_type(8)));
typedef float v4f  __attribute__((ext_vector_type(4)));

__device__ __forceinline__ float bf_lo(uint32_t u){ return __uint_as_float(u << 16); }
__device__ __forceinline__ float bf_hi(uint32_t u){ return __uint_as_float(u & 0xffff0000u); }

__device__ __forceinline__ uint16_t f2bf(float f) {
    uint32_t u = __float_as_uint(f);
    uint32_t lsb = (u >> 16) & 1u;
    u += 0x7fffu + lsb;
    return (uint16_t)(u >> 16);
}

// Load element i of a buffer whose dtype is bf16 (isbf=1) or f32 (isbf=0), as float.
__device__ __forceinline__ float ld_f(const void* p, size_t i, int isbf) {
    if (isbf) {
        uint32_t b = ((const uint16_t*)p)[i];
        return __uint_as_float(b << 16);
    }
    return ((const float*)p)[i];
}
__device__ __forceinline__ uint16_t ld_bf_bits(const void* p, size_t i, int isbf) {
    if (isbf) return ((const uint16_t*)p)[i];
    return f2bf(((const float*)p)[i]);
}

// ---------------- dtype sniffer ---------------------------------------------------------
__global__ void detect_kernel(const uint16_t* __restrict__ w, int* __restrict__ flag)
{
    int i = threadIdx.x;  // 0..63
    uint32_t bits = w[2 * i];
    float f = __uint_as_float(bits << 16);
    float a = fabsf(f);
    bool ok = (a >= 1e-10f && a <= 1e5f);
    unsigned long long m = __ballot(ok);
    if (i == 0) flag[0] = (__popcll(m) >= 48) ? 1 : 0;
}

// ---------------- prep: layout transforms -----------------------------------------------
__global__ void prep_kernel(const void* __restrict__ g,
                            const void* __restrict__ w1,
                            const void* __restrict__ b1,
                            const void* __restrict__ w2,
                            const void* __restrict__ b2,
                            const void* __restrict__ rw,
                            const void* __restrict__ tw,
                            const void* __restrict__ a1w,
                            const void* __restrict__ a1b,
                            const void* __restrict__ a2w,
                            const void* __restrict__ a2b,
                            const int* __restrict__ flag,
                            uint16_t* __restrict__ grid_cl,
                            float* __restrict__ wT1, float* __restrict__ bias1,
                            uint16_t* __restrict__ w2t, float* __restrict__ bias2,
                            uint16_t* __restrict__ wrt,
                            float* __restrict__ wA1, float* __restrict__ bA1,
                            float* __restrict__ wA2, float* __restrict__ bA2)
{
    constexpr int N_GRID = NB * GN * GN * NC;        // 614656
    constexpr int N_WT1  = 9 * NC * NH;              // 2700
    constexpr int N_B1   = NH;
    constexpr int N_W2T  = 9 * CIP * CIP;            // 230400
    constexpr int N_B2   = CIP;
    constexpr int N_WRT  = 9 * 80 * CIP;             // 115200
    constexpr int N_A1W  = NH * NA;
    constexpr int N_A1B  = NH;
    constexpr int N_A2W  = NA * NH;
    constexpr int N_A2B  = NA;

    int isbf = flag[0];
    int i = blockIdx.x * blockDim.x + threadIdx.x;
    if (i < N_GRID) {
        int c = i & 1; int s = (i >> 1) % (GN*GN); int b = i / (GN*GN*2);
        grid_cl[i] = ld_bf_bits(g, (size_t)(b*NC + c)*(GN*GN) + s, isbf);
        return;
    }
    i -= N_GRID;
    if (i < N_WT1) {
        int co = i % NH; int r = i / NH; int ci = r & 1; int k = r >> 1;
        wT1[i] = ld_f(w1, (size_t)co*(NC*9) + ci*9 + k, isbf);
        return;
    }
    i -= N_WT1;
    if (i < N_B1) { bias1[i] = ld_f(b1, i, isbf); return; }
    i -= N_B1;
    if (i < N_W2T) {
        int ci = i % CIP; int r = i / CIP; int co = r % CIP; int tap = r / CIP;
        uint16_t v = 0;
        if (co < NH && ci < NH)
            v = f2bf(ld_f(w2, ((size_t)co*NH + ci)*9 + tap, isbf));
        w2t[i] = v;
        return;
    }
    i -= N_W2T;
    if (i < N_B2) { bias2[i] = (i < NH) ? ld_f(b2, i, isbf) : 0.f; return; }
    i -= N_B2;
    if (i < N_WRT) {
        int ci = i % CIP; int r = i / CIP; int co = r % 80; int tap = r / 80;
        uint16_t v = 0;
        if (ci < NH) {
            if (co == 0)           v = f2bf(ld_f(rw, (size_t)ci*9 + tap, isbf));
            else if (co <= 72)     v = f2bf(ld_f(tw, ((size_t)(co-1)*NH + ci)*9 + tap, isbf));
        }
        wrt[i] = v;
        return;
    }
    i -= N_WRT;
    if (i < N_A1W) { wA1[i] = ld_f(a1w, i, isbf); return; }
    i -= N_A1W;
    if (i < N_A1B) { bA1[i] = ld_f(a1b, i, isbf); return; }
    i -= N_A1B;
    if (i < N_A2W) { wA2[i] = ld_f(a2w, i, isbf); return; }
    i -= N_A2W;
    if (i < N_A2B) { bA2[i] = ld_f(a2b, i, isbf); return; }
}

// ---------------- conv1: 2->150 VALU, writes 160-padded bf16 ----------------------------
__global__ __launch_bounds__(192)
void conv1_cl(const uint16_t* __restrict__ in,   // [b][49][49][2] bf16
              const float* __restrict__ wT,      // [(k*2+ci)*150+co]
              const float* __restrict__ bias,    // f32 [150]
              uint16_t* __restrict__ out)        // [b][49][49][160] bf16
{
    constexpr int H = GN, XG = 13;
    int bid = blockIdx.x;
    int xg = bid % XG;
    int y  = (bid / XG) % H;
    int b  = bid / (XG * H);
    int x0 = xg * 4;
    int co = threadIdx.x;

    if (co >= NH) {
        if (co < CIP) {
            #pragma unroll
            for (int xi = 0; xi < 4; ++xi) {
                int x = x0 + xi;
                if (x < H) out[((size_t)(b*H + y)*H + x)*CIP + co] = 0;
            }
        }
        return;
    }

    float bv = bias[co];
    float acc[4] = {bv, bv, bv, bv};

    for (int ky = 0; ky < 3; ++ky) {
        int yy = y + ky - 1;
        if (yy < 0 || yy >= H) continue;
        const uint16_t* rowp = in + (size_t)(b * H + yy) * H * NC;
        #pragma unroll
        for (int kx = 0; kx < 3; ++kx) {
            const float* wp = wT + ((ky*3 + kx) * NC) * NH + co;
            float w0 = wp[0];
            float w1 = wp[NH];
            #pragma unroll
            for (int xi = 0; xi < 4; ++xi) {
                int xx = x0 + xi + kx - 1;
                if (xx < 0 || xx >= H) continue;
                uint32_t u = *(const uint32_t*)(rowp + (size_t)xx * NC);
                acc[xi] += bf_lo(u)*w0 + bf_hi(u)*w1;
            }
        }
    }
    #pragma unroll
    for (int xi = 0; xi < 4; ++xi) {
        int x = x0 + xi;
        if (x < H) out[((size_t)(b*H + y)*H + x)*CIP + co] = f2bf(fmaxf(acc[xi], 0.f));
    }
}

// ---------------- MFMA implicit-GEMM 3x3 conv -------------------------------------------
template<int CO_T, int PAD, int OH, bool RELU, bool OBF>
__global__ __launch_bounds__(192)
void conv_mfma(const uint16_t* __restrict__ in,
               const uint16_t* __restrict__ wt,
               const float* __restrict__ bias,
               void* __restrict__ outv)
{
    constexpr int H = GN;
    constexpr int NSUB = CO_T / 16;
    constexpr int RG = 9, XG = 4;
    constexpr int ASTR = 168;
    static_assert(NSUB * 16 == CO_T, "");

    __shared__ __align__(16) uint16_t shA[8 * 18 * ASTR];
    __shared__ __align__(16) uint16_t shB[CO_T * 40];

    int bid = blockIdx.x;
    int xg = bid & 3;
    int rg = (bid >> 2) % RG;
    int b  = bid / (RG * XG);
    int y0 = rg * 6, x0 = xg * 16;
    int t = threadIdx.x;
    int w = t >> 6, l = t & 63;

    for (int q = t; q < 8*18*20; q += 192) {
        int ci8 = q % 20;
        int c   = (q / 20) % 18;
        int r   = q / 360;
        int yy = y0 + r - PAD;
        int xx = x0 + c - PAD;
        uint4 val = make_uint4(0u, 0u, 0u, 0u);
        if (yy >= 0 && yy < H && xx >= 0 && xx < H)
            val = *(const uint4*)(in + ((size_t)(b*H + yy)*H + xx)*CIP + ci8*8);
        *(uint4*)(shA + (r*18 + c)*ASTR + ci8*8) = val;
    }

    v4f acc[2][NSUB];
    #pragma unroll
    for (int s = 0; s < 2; ++s)
        #pragma unroll
        for (int n = 0; n < NSUB; ++n)
            acc[s][n] = (v4f){0.f, 0.f, 0.f, 0.f};

    int lo16 = l & 15, q4 = l >> 4;

    for (int tap = 0; tap < 9; ++tap) {
        int ky = tap / 3, kx = tap % 3;
        for (int kc = 0; kc < 5; ++kc) {
            if (tap | kc) __syncthreads();
            for (int q = t; q < CO_T*4; q += 192) {
                int c4 = q & 3, co = q >> 2;
                uint4 v = *(const uint4*)(wt + ((size_t)tap*CO_T + co)*CIP + kc*32 + c4*8);
                *(uint4*)(shB + co*40 + c4*8) = v;
            }
            __syncthreads();

            int ci = kc*32 + q4*8;
            v8bf afr[2];
            #pragma unroll
            for (int s = 0; s < 2; ++s) {
                int r = 2*w + s + ky;
                int c = lo16 + kx;
                afr[s] = *(const v8bf*)(shA + (r*18 + c)*ASTR + ci);
            }
            #pragma unroll
            for (int n = 0; n < NSUB; ++n) {
                v8bf bfr = *(const v8bf*)(shB + (n*16 + lo16)*40 + q4*8);
                acc[0][n] = __builtin_amdgcn_mfma_f32_16x16x32_bf16(afr[0], bfr, acc[0][n], 0, 0, 0);
                acc[1][n] = __builtin_amdgcn_mfma_f32_16x16x32_bf16(afr[1], bfr, acc[1][n], 0, 0, 0);
            }
        }
    }

    #pragma unroll
    for (int s = 0; s < 2; ++s) {
        int y = y0 + 2*w + s;
        if (y >= OH) continue;
        #pragma unroll
        for (int n = 0; n < NSUB; ++n) {
            int co = n*16 + lo16;
            float bv = bias ? bias[co] : 0.f;
            #pragma unroll
            for (int r = 0; r < 4; ++r) {
                int x = x0 + q4*4 + r;
                if (x >= OH) continue;
                float v = acc[s][n][r] + bv;
                if (RELU) v = fmaxf(v, 0.f);
                if (OBF) {
                    ((uint16_t*)outv)[((size_t)(b*OH + y)*OH + x)*CIP + co] = f2bf(v);
                } else {
                    if (co < RTC)
                        ((float*)outv)[((size_t)(b*OH + y)*OH + x)*RTC + co] = v;
                }
            }
        }
    }
}

// ---------------- softmax + u16 fixed-point pack ----------------------------------------
// rt [b][p][73] f32 -> sTu [b][p][36] dwords (72 u16, idx = a*9+k; dword j holds idx 2j
// (lo) and 2j+1 (hi)), rewb [b][p] f32.
__global__ void softmax_pack_kernel(const float* __restrict__ rt,
                                    uint32_t* __restrict__ sTu,
                                    float* __restrict__ rewb)
{
    int idx = blockIdx.x * blockDim.x + threadIdx.x;
    constexpr int TOT = NB * NP;
    if (idx >= TOT) return;
    const float* tp = rt + (size_t)idx * RTC;
    rewb[idx] = tp[0];
    uint32_t words[36];
    #pragma unroll
    for (int a = 0; a < NA; ++a) {
        const float* s = tp + 1 + a * 9;
        float v[9];
        float m = -1e30f;
        #pragma unroll
        for (int k = 0; k < 9; ++k) { v[k] = s[k]; m = fmaxf(m, v[k]); }
        float sum = 0.f;
        #pragma unroll
        for (int k = 0; k < 9; ++k) { v[k] = expf(v[k] - m); sum += v[k]; }
        float sc = 65535.f / sum;
        #pragma unroll
        for (int k = 0; k < 9; ++k) {
            int gi = a * 9 + k;
            uint32_t u = (uint32_t)__float2uint_rn(v[k] * sc);
            if (gi & 1) words[gi >> 1] |= (u << 16);
            else        words[gi >> 1] = u;
        }
    }
    uint32_t* op = sTu + (size_t)idx * 36;
    #pragma unroll
    for (int j = 0; j < 9; ++j)
        *(uint4*)(op + 4*j) = make_uint4(words[4*j], words[4*j+1], words[4*j+2], words[4*j+3]);
}

// ---------------- VI inner: one action-pair (9 dwords = 18 u16 taps) --------------------
__device__ __forceinline__ void vi_pair(const uint32_t* d, const float* pat,
                                        float r, float& qE, float& qO)
{
    float qe = 0.f, qo = 0.f;
    qe = fmaf((float)(d[0] & 0xffffu), pat[0], qe);
    qe = fmaf((float)(d[0] >> 16),     pat[1], qe);
    qe = fmaf((float)(d[1] & 0xffffu), pat[2], qe);
    qe = fmaf((float)(d[1] >> 16),     pat[3], qe);
    qe = fmaf((float)(d[2] & 0xffffu), pat[4], qe);
    qe = fmaf((float)(d[2] >> 16),     pat[5], qe);
    qe = fmaf((float)(d[3] & 0xffffu), pat[6], qe);
    qe = fmaf((float)(d[3] >> 16),     pat[7], qe);
    qe = fmaf((float)(d[4] & 0xffffu), pat[8], qe);
    qo = fmaf((float)(d[4] >> 16),     pat[0], qo);
    qo = fmaf((float)(d[5] & 0xffffu), pat[1], qo);
    qo = fmaf((float)(d[5] >> 16),     pat[2], qo);
    qo = fmaf((float)(d[6] & 0xffffu), pat[3], qo);
    qo = fmaf((float)(d[6] >> 16),     pat[4], qo);
    qo = fmaf((float)(d[7] & 0xffffu), pat[5], qo);
    qo = fmaf((float)(d[7] >> 16),     pat[6], qo);
    qo = fmaf((float)(d[8] & 0xffffu), pat[7], qo);
    qo = fmaf((float)(d[8] >> 16),     pat[8], qo);
    constexpr float inv = 1.f / 65535.f;
    qE = fmaf(qe, inv, r);
    qO = fmaf(qo, inv, r);
}

// ---------------- persistent value iteration: sT register-resident ----------------------
// One block (1024 thr) per batch. Thread t owns p = t and t+1024 with sT in VGPRs;
// positions 2048..2600 (threads 0..552) stream their sT from L2 each iteration.
__global__ __launch_bounds__(1024, 1)
void vi_kernel(const uint32_t* __restrict__ sTu, const float* __restrict__ rewb,
               float* __restrict__ qout)
{
    __shared__ float vb[2][53*53];
    __shared__ float rew[NP];
    int b = blockIdx.x, t = threadIdx.x;
    for (int i = t; i < 53*53; i += 1024) { vb[0][i] = 0.f; vb[1][i] = 0.f; }
    const uint32_t* sb = sTu + (size_t)b * NP * 36;
    for (int i = t; i < NP; i += 1024) rew[i] = rewb[(size_t)b * NP + i];

    int p0 = t, p1 = t + 1024, p2 = t + 2048;
    uint32_t s0[36], s1[36];
    {
        const uint4* a0 = (const uint4*)(sb + (size_t)p0 * 36);
        const uint4* a1 = (const uint4*)(sb + (size_t)p1 * 36);
        #pragma unroll
        for (int j = 0; j < 9; ++j) {
            uint4 v = a0[j];
            s0[4*j+0]=v.x; s0[4*j+1]=v.y; s0[4*j+2]=v.z; s0[4*j+3]=v.w;
            uint4 u = a1[j];
            s1[4*j+0]=u.x; s1[4*j+1]=u.y; s1[4*j+2]=u.z; s1[4*j+3]=u.w;
        }
    }
    __syncthreads();

    float* qb = qout + (size_t)b * NP * NA;
    int cur = 0;
    for (int it = 0; it < KIT; ++it) {
        bool last = (it == KIT - 1);
        const float* vc = vb[cur];
        float* vn = vb[cur ^ 1];
        // ---- p0 (registers)
        {
            int y = p0 / HPN, x = p0 % HPN;
            float pat[9];
            #pragma unroll
            for (int dy = 0; dy < 3; ++dy)
                #pragma unroll
                for (int dx = 0; dx < 3; ++dx)
                    pat[dy*3+dx] = vc[(y+dy)*53 + x+dx];
            float r = rew[p0];
            float best = -3.4e38f;
            #pragma unroll
            for (int ap = 0; ap < 4; ++ap) {
                float qE, qO;
                vi_pair(s0 + ap*9, pat, r, qE, qO);
                best = fmaxf(best, fmaxf(qE, qO));
                if (last) {
                    qb[(size_t)p0*NA + 2*ap]     = qE;
                    qb[(size_t)p0*NA + 2*ap + 1] = qO;
                }
            }
            vn[(y+1)*53 + x+1] = best;
        }
        // ---- p1 (registers)
        {
            int y = p1 / HPN, x = p1 % HPN;
            float pat[9];
            #pragma unroll
            for (int dy = 0; dy < 3; ++dy)
                #pragma unroll
                for (int dx = 0; dx < 3; ++dx)
                    pat[dy*3+dx] = vc[(y+dy)*53 + x+dx];
            float r = rew[p1];
            float best = -3.4e38f;
            #pragma unroll
            for (int ap = 0; ap < 4; ++ap) {
                float qE, qO;
                vi_pair(s1 + ap*9, pat, r, qE, qO);
                best = fmaxf(best, fmaxf(qE, qO));
                if (last) {
                    qb[(size_t)p1*NA + 2*ap]     = qE;
                    qb[(size_t)p1*NA + 2*ap + 1] = qO;
                }
            }
            vn[(y+1)*53 + x+1] = best;
        }
        // ---- p2 (tail, streamed from L2)
        if (t < NP - 2048) {
            int y = p2 / HPN, x = p2 % HPN;
            float pat[9];
            #pragma unroll
            for (int dy = 0; dy < 3; ++dy)
                #pragma unroll
                for (int dx = 0; dx < 3; ++dx)
                    pat[dy*3+dx] = vc[(y+dy)*53 + x+dx];
            float r = rew[p2];
            float best = -3.4e38f;
            const uint32_t* gp = sb + (size_t)p2 * 36;
            #pragma unroll
            for (int ap = 0; ap < 4; ++ap) {
                uint32_t d[9];
                #pragma unroll
                for (int j = 0; j < 9; ++j) d[j] = gp[ap*9 + j];
                float qE, qO;
                vi_pair(d, pat, r, qE, qO);
                best = fmaxf(best, fmaxf(qE, qO));
                if (last) {
                    qb[(size_t)p2*NA + 2*ap]     = qE;
                    qb[(size_t)p2*NA + 2*ap + 1] = qO;
                }
            }
            vn[(y+1)*53 + x+1] = best;
        }
        __syncthreads();
        cur ^= 1;
    }
}

// ---------------- fused MLP head: q(8) -> relu(150) -> logits(8) -------------------------
__global__ void head_kernel(const float* __restrict__ q,
                            const float* __restrict__ wA1,
                            const float* __restrict__ bA1,
                            const float* __restrict__ wA2,
                            const float* __restrict__ bA2,
                            const int* __restrict__ flag,
                            void* __restrict__ out)
{
    __shared__ float w1[NH*NA], sb1[NH], w2[NA*NH], sb2[NA];
    int t = threadIdx.x;
    for (int i = t; i < NH*NA; i += 256) w1[i] = wA1[i];
    for (int i = t; i < NH;    i += 256) sb1[i] = bA1[i];
    for (int i = t; i < NA*NH; i += 256) w2[i] = wA2[i];
    if (t < NA) sb2[t] = bA2[t];
    __syncthreads();

    int isbf = flag[0];
    int idx = blockIdx.x * 256 + t;
    constexpr int TOT = NB * GN * GN;
    if (idx >= TOT) return;
    int x = idx % GN, y = (idx / GN) % GN, b = idx / (GN*GN);
    const float* qp = q + ((size_t)(b*HPN + y)*HPN + x) * NA;
    float qv[NA];
    #pragma unroll
    for (int a = 0; a < NA; ++a) qv[a] = qp[a];
    float lg[NA];
    #pragma unroll
    for (int a = 0; a < NA; ++a) lg[a] = sb2[a];
    for (int c = 0; c < NH; ++c) {
        float m = sb1[c];
        #pragma unroll
        for (int a = 0; a < NA; ++a) m += qv[a] * w1[c*NA + a];
        m = fmaxf(m, 0.f);
        #pragma unroll
        for (int a = 0; a < NA; ++a) lg[a] += m * w2[a*NH + c];
    }
    #pragma unroll
    for (int a = 0; a < NA; ++a) {
        size_t oi = ((size_t)(b*NA + a)*GN + y)*GN + x;
        float r = lg[a];
        if (isbf) ((uint16_t*)out)[oi] = f2bf(r);
        else      ((float*)out)[oi] = r;
    }
}

extern "C" void kernel_launch(void* const* d_in, const int* in_sizes, int n_in,
                              void* d_out, int out_size, void* d_ws, size_t ws_size,
                              hipStream_t stream)
{
    const void* g   = d_in[0];
    const void* h1w = d_in[3];
    const void* h1b = d_in[4];
    const void* h2w = d_in[5];
    const void* h2b = d_in[6];
    const void* rw  = d_in[7];
    const void* tw  = d_in[8];
    const void* a1w = d_in[9];
    const void* a1b = d_in[10];
    const void* a2w = d_in[11];
    const void* a2b = d_in[12];

    char* ws = (char*)d_ws;
    size_t off = 0;
    auto take = [&](size_t bytes) { size_t r = off; off = (off + bytes + 255) & ~(size_t)255; return r; };

    constexpr size_t N_GRID_CL = (size_t)NB*GN*GN*NC;           // bf16
    constexpr size_t N_WT1  = 9*NC*NH;                          // f32
    constexpr size_t N_B1   = NH;
    constexpr size_t N_W2T  = 9*CIP*CIP;                        // bf16
    constexpr size_t N_B2   = CIP;
    constexpr size_t N_WRT  = 9*80*CIP;                         // bf16
    constexpr size_t N_A1W  = NH*NA;
    constexpr size_t N_A1B  = NH;
    constexpr size_t N_A2W  = NA*NH;
    constexpr size_t N_A2B  = NA;
    constexpr size_t N_H    = (size_t)NB*GN*GN*CIP;             // bf16 (h1 / h2, padded)
    constexpr size_t N_RT   = (size_t)NB*NP*RTC;                // f32
    constexpr size_t N_Q    = (size_t)NB*NP*NA;                 // f32
    constexpr size_t N_STU  = (size_t)NB*NP*36;                 // u32 packed sT
    constexpr size_t N_REWB = (size_t)NB*NP;                    // f32

    size_t off_flag   = take(4);
    size_t off_gridcl = take(N_GRID_CL * 2);
    size_t off_wT1    = take(N_WT1 * 4);
    size_t off_b1     = take(N_B1 * 4);
    size_t off_w2t    = take(N_W2T * 2);
    size_t off_b2     = take(N_B2 * 4);
    size_t off_wrt    = take(N_WRT * 2);
    size_t off_wA1    = take(N_A1W * 4);
    size_t off_bA1    = take(N_A1B * 4);
    size_t off_wA2    = take(N_A2W * 4);
    size_t off_bA2    = take(N_A2B * 4);
    size_t off_q      = take(N_Q * 4);
    // region A: h1 (bf16, padded) first; later reused for rt (f32) after conv2 consumed h1
    size_t szA = (N_RT * 4 > N_H * 2) ? N_RT * 4 : N_H * 2;
    size_t off_A      = take(szA);
    // region B: h2 (bf16, padded); after convRT consumes h2, reused for sTu + rewb
    size_t szB = N_H * 2;
    size_t szB2 = ((N_STU * 4 + 255) & ~(size_t)255) + N_REWB * 4;
    if (szB2 > szB) szB = szB2;
    size_t off_B      = take(szB);

    int*      flag    = (int*)(ws + off_flag);
    uint16_t* grid_cl = (uint16_t*)(ws + off_gridcl);
    float*    wT1     = (float*)(ws + off_wT1);
    float*    bias1   = (float*)(ws + off_b1);
    uint16_t* w2t     = (uint16_t*)(ws + off_w2t);
    float*    bias2   = (float*)(ws + off_b2);
    uint16_t* wrt     = (uint16_t*)(ws + off_wrt);
    float*    wA1     = (float*)(ws + off_wA1);
    float*    bA1     = (float*)(ws + off_bA1);
    float*    wA2     = (float*)(ws + off_wA2);
    float*    bA2     = (float*)(ws + off_bA2);
    float*    qbuf    = (float*)(ws + off_q);
    uint16_t* h1      = (uint16_t*)(ws + off_A);
    float*    rt      = (float*)(ws + off_A);
    uint16_t* h2      = (uint16_t*)(ws + off_B);
    uint32_t* sTu     = (uint32_t*)(ws + off_B);
    float*    rewb    = (float*)(ws + off_B + ((N_STU * 4 + 255) & ~(size_t)255));

    // 0. dtype detection (bf16 vs f32 inputs)
    detect_kernel<<<1, 64, 0, stream>>>((const uint16_t*)h2w, flag);
    // 1. layout prep + dtype conversion
    {
        int total = (int)(N_GRID_CL + N_WT1 + N_B1 + N_W2T + N_B2 + N_WRT
                          + N_A1W + N_A1B + N_A2W + N_A2B);
        prep_kernel<<<(total + 255)/256, 256, 0, stream>>>(
            g, h1w, h1b, h2w, h2b, rw, tw, a1w, a1b, a2w, a2b, flag,
            grid_cl, wT1, bias1, w2t, bias2, wrt, wA1, bA1, wA2, bA2);
    }
    // 2. conv1: 2->150 VALU, out [b][49][49][160] bf16
    conv1_cl<<<NB*GN*13, 192, 0, stream>>>(grid_cl, wT1, bias1, h1);
    // 3. conv2: 150->150 MFMA implicit GEMM, out h2 padded bf16
    conv_mfma<CIP, 1, GN, true, true>
        <<<NB*9*4, 192, 0, stream>>>(h1, w2t, bias2, (void*)h2);
    // 4. reward+trans: 150->73 MFMA, pad 2, out 51x51 f32 (overwrites h1 region)
    conv_mfma<80, 2, HPN, false, false>
        <<<NB*9*4, 192, 0, stream>>>(h2, wrt, nullptr, (void*)rt);
    // 5. softmax + u16 pack (h2 dead -> overwritten by sTu/rewb)
    softmax_pack_kernel<<<(NB*NP + 255)/256, 256, 0, stream>>>(rt, sTu, rewb);
    // 6. value iteration (persistent, one block per batch, sT register-resident)
    vi_kernel<<<NB, 1024, 0, stream>>>(sTu, rewb, qbuf);
    // 7. head
    head_kernel<<<(NB*GN*GN + 255)/256, 256, 0, stream>>>(qbuf, wA1, bA1, wA2, bA2, flag,
                                                          d_out);
}